// Round 2
// baseline (1480.075 us; speedup 1.0000x reference)
//
#include <hip/hip_runtime.h>
#include <stdint.h>

#define D 128
#define H 256
#define LSTR 264   // LDS row stride in shorts (padded vs 256 to break bank conflicts)

typedef short s8v __attribute__((ext_vector_type(8)));   // 8 x bf16 fragment (4 VGPRs)
typedef float f4v __attribute__((ext_vector_type(4)));   // 4 x f32 accumulator

__device__ __forceinline__ short f2bf(float f){
  union { float f; unsigned u; } v; v.f = f;
  unsigned r = v.u + 0x7fffu + ((v.u >> 16) & 1u);       // round-to-nearest-even
  return (short)(r >> 16);
}

// ---- prep: swizzle W1,W2 into bf16 MFMA B-fragment order; zero stat shadows ----
// B-frag layout for mfma_f32_16x16x32_bf16: lane l holds B[k][n], n = l&15,
// k = (l>>4)*8 + j (j=0..7 contiguous). Frag id = jt*KT + kt, 64 lanes * 8 bf16.
__global__ void k_prep(const float* __restrict__ W1, const float* __restrict__ W2,
                       short* __restrict__ W1s, short* __restrict__ W2s,
                       float* __restrict__ st1, float* __restrict__ st2){
  int t = blockIdx.x*256 + threadIdx.x;
  if (t < 32768){                               // W1 [H=256][D=128], 16 jt x 4 kt
    int j = t & 7, lane = (t>>3) & 63, kt = (t>>9) & 3, jt = t>>11;
    int col = jt*16 + (lane & 15);
    int k   = kt*32 + (lane>>4)*8 + j;
    W1s[t] = f2bf(W1[col*D + k]);
  } else if (t < 65536){                        // W2 [D=128][H=256], 8 jt x 8 kt
    int u = t - 32768;
    int j = u & 7, lane = (u>>3) & 63, kt = (u>>9) & 7, jt = u>>12;
    int col = jt*16 + (lane & 15);
    int k   = kt*32 + (lane>>4)*8 + j;
    W2s[u] = f2bf(W2[col*H + k]);
  } else {
    int u = t - 65536;
    if (u < 32*2*H) st1[u] = 0.f;
    else if (u < 32*2*H + 32*2*D) st2[u - 32*2*H] = 0.f;
  }
}

// ---- h = (1 + eps - deg) * x   (h lives in d_out) ----
__global__ void k_init_h(const float* __restrict__ x, const float* __restrict__ deg,
                         const float* __restrict__ eps, float* __restrict__ h, int total4){
  int t = blockIdx.x*256 + threadIdx.x;
  if (t >= total4) return;
  int n = t >> 5;                               // D/4 = 32 float4 per row
  float s = 1.0f + eps[0] - deg[n];
  float4 v = ((const float4*)x)[t];
  v.x*=s; v.y*=s; v.z*=s; v.w*=s;
  ((float4*)h)[t] = v;
}

// ---- edge scatter: h[s] += m, h[d] += m, m = x[s]+x[d]+ea[e]. One wave/edge. ----
__global__ void k_scatter(const float* __restrict__ x, const float* __restrict__ ea,
                          const int* __restrict__ src, const int* __restrict__ dst,
                          float* __restrict__ h, int E_){
  int e = (blockIdx.x*256 + threadIdx.x) >> 6;
  int lane = threadIdx.x & 63;
  if (e >= E_) return;
  int s = src[e], d = dst[e];
  float2 a = ((const float2*)(x + (size_t)s*D))[lane];
  float2 b = ((const float2*)(x + (size_t)d*D))[lane];
  float2 m = ((const float2*)(ea + (size_t)e*D))[lane];
  float mx = a.x + b.x + m.x;
  float my = a.y + b.y + m.y;
  float* hs = h + (size_t)s*D + lane*2;
  float* hd = h + (size_t)d*D + lane*2;
  atomicAdd(hs,   mx); atomicAdd(hs+1, my);
  atomicAdd(hd,   mx); atomicAdd(hd+1, my);
}

// ---- GEMM1 stats-only: col sums / sumsq of Y1 = h @ W1^T (Y1 never stored) ----
__global__ void k_gemm1(const float* __restrict__ h, const short* __restrict__ W1s,
                        float* __restrict__ st1, int nW){
  int wid = (blockIdx.x*256 + threadIdx.x) >> 6;
  int lane = threadIdx.x & 63;
  if (wid >= nW) return;
  int r0 = wid*16;
  int mrow = lane & 15, kg = lane >> 4;
  const float* hrow = h + (size_t)(r0 + mrow)*D + kg*8;
  s8v af[4];
#pragma unroll
  for (int kt=0; kt<4; kt++){
    float4 v0 = *(const float4*)(hrow + kt*32);
    float4 v1 = *(const float4*)(hrow + kt*32 + 4);
    s8v a;
    a[0]=f2bf(v0.x); a[1]=f2bf(v0.y); a[2]=f2bf(v0.z); a[3]=f2bf(v0.w);
    a[4]=f2bf(v1.x); a[5]=f2bf(v1.y); a[6]=f2bf(v1.z); a[7]=f2bf(v1.w);
    af[kt] = a;
  }
  const s8v* Bf = (const s8v*)W1s;
  int shadow = wid & 31;
#pragma unroll
  for (int jt=0; jt<16; jt++){
    f4v acc = {0.f,0.f,0.f,0.f};
#pragma unroll
    for (int kt=0; kt<4; kt++)
      acc = __builtin_amdgcn_mfma_f32_16x16x32_bf16(af[kt], Bf[(jt*4+kt)*64 + lane], acc, 0, 0, 0);
    float s = 0.f, q = 0.f;
#pragma unroll
    for (int r=0; r<4; r++){ s += acc[r]; q += acc[r]*acc[r]; }
    s += __shfl_xor(s, 16); s += __shfl_xor(s, 32);
    q += __shfl_xor(q, 16); q += __shfl_xor(q, 32);
    if (lane < 16){
      atomicAdd(&st1[shadow*(2*H) + jt*16 + lane], s);
      atomicAdd(&st1[shadow*(2*H) + H + jt*16 + lane], q);
    }
  }
}

__global__ void k_fin1(const float* __restrict__ st1, const float* __restrict__ g,
                       const float* __restrict__ b, float* __restrict__ a,
                       float* __restrict__ c, float invN){
  int j = threadIdx.x;                          // H threads
  float s=0.f, q=0.f;
  for (int i=0;i<32;i++){ s += st1[i*(2*H) + j]; q += st1[i*(2*H) + H + j]; }
  float mu = s*invN;
  float var = q*invN - mu*mu;
  float rs = rsqrtf(var + 1e-5f);
  float aa = g[j]*rs;
  a[j] = aa; c[j] = b[j] - mu*aa;
}

// ---- GEMM2 fused: recompute Y1 tile, BN1+ReLU, LDS transpose (C->A layout),
//      second MFMA chain, Y2 overwrites own h rows in d_out, BN2 stats. ----
__launch_bounds__(256)
__global__ void k_gemm2(const float* __restrict__ h, const short* __restrict__ W1s,
                        const short* __restrict__ W2s,
                        const float* __restrict__ a1, const float* __restrict__ c1,
                        float* __restrict__ Y2, float* __restrict__ st2, int nW){
  __shared__ short P[4*16*LSTR];                // 33792 B: per-wave 16x256 bf16 tile (padded)
  int wib  = threadIdx.x >> 6;
  int lane = threadIdx.x & 63;
  int wid  = blockIdx.x*4 + wib;
  bool valid = wid < nW;
  int r0 = wid*16;
  int mrow = lane & 15, kg = lane >> 4;
  short* Pw = P + wib*16*LSTR;

  // 1. h rows -> bf16 A-frags (identical to k_gemm1 => BN1 stats consistent)
  s8v af[4];
#pragma unroll
  for (int kt=0; kt<4; kt++){ s8v z = {0,0,0,0,0,0,0,0}; af[kt] = z; }
  if (valid){
    const float* hrow = h + (size_t)(r0 + mrow)*D + kg*8;
#pragma unroll
    for (int kt=0; kt<4; kt++){
      float4 v0 = *(const float4*)(hrow + kt*32);
      float4 v1 = *(const float4*)(hrow + kt*32 + 4);
      s8v a;
      a[0]=f2bf(v0.x); a[1]=f2bf(v0.y); a[2]=f2bf(v0.z); a[3]=f2bf(v0.w);
      a[4]=f2bf(v1.x); a[5]=f2bf(v1.y); a[6]=f2bf(v1.z); a[7]=f2bf(v1.w);
      af[kt] = a;
    }
  }

  // 2. recompute Y1 tile per jt, BN1+ReLU, write bf16 into LDS (C-layout positions)
  const s8v* B1 = (const s8v*)W1s;
#pragma unroll
  for (int jt=0; jt<16; jt++){
    f4v acc = {0.f,0.f,0.f,0.f};
#pragma unroll
    for (int kt=0; kt<4; kt++)
      acc = __builtin_amdgcn_mfma_f32_16x16x32_bf16(af[kt], B1[(jt*4+kt)*64 + lane], acc, 0, 0, 0);
    int col = jt*16 + mrow;
    float a = a1[col], c = c1[col];
#pragma unroll
    for (int r=0; r<4; r++){
      float e = fmaxf(acc[r]*a + c, 0.f);
      Pw[(kg*4 + r)*LSTR + col] = f2bf(e);
    }
  }
  __syncthreads();

  // 3. read back in A-frag layout: lane holds row m=lane&15, k = kt2*32 + kg*8 + j
  s8v af2[8];
#pragma unroll
  for (int kt2=0; kt2<8; kt2++)
    af2[kt2] = *(const s8v*)(Pw + mrow*LSTR + kt2*32 + kg*8);

  // 4. second GEMM + BN2 stats; Y2 overwrites this wave's own (dead) h rows
  const s8v* B2 = (const s8v*)W2s;
  int shadow = wid & 31;
#pragma unroll
  for (int jt=0; jt<8; jt++){
    f4v acc = {0.f,0.f,0.f,0.f};
#pragma unroll
    for (int kt2=0; kt2<8; kt2++)
      acc = __builtin_amdgcn_mfma_f32_16x16x32_bf16(af2[kt2], B2[(jt*8+kt2)*64 + lane], acc, 0, 0, 0);
    float s=0.f, q=0.f;
    if (valid){
#pragma unroll
      for (int r=0; r<4; r++){
        int row = r0 + kg*4 + r;
        Y2[(size_t)row*D + jt*16 + mrow] = acc[r];
        s += acc[r]; q += acc[r]*acc[r];
      }
    }
    s += __shfl_xor(s,16); s += __shfl_xor(s,32);
    q += __shfl_xor(q,16); q += __shfl_xor(q,32);
    if (valid && lane < 16){
      atomicAdd(&st2[shadow*(2*D) + jt*16 + lane], s);
      atomicAdd(&st2[shadow*(2*D) + D + jt*16 + lane], q);
    }
  }
}

__global__ void k_fin2(const float* __restrict__ st2, const float* __restrict__ g,
                       const float* __restrict__ b, float* __restrict__ a,
                       float* __restrict__ c, float invN){
  int j = threadIdx.x;                          // D threads
  float s=0.f, q=0.f;
  for (int i=0;i<32;i++){ s += st2[i*(2*D) + j]; q += st2[i*(2*D) + D + j]; }
  float mu = s*invN;
  float var = q*invN - mu*mu;
  float rs = rsqrtf(var + 1e-5f);
  float aa = g[j]*rs;
  a[j] = aa; c[j] = b[j] - mu*aa;
}

// ---- out = relu(Y2*a2 + c2), in place on d_out ----
__global__ void k_final(const float* __restrict__ Y2, const float* __restrict__ a2,
                        const float* __restrict__ c2, float* __restrict__ out, int total4){
  int t = blockIdx.x*256 + threadIdx.x;
  if (t >= total4) return;
  int d4 = t & 31;
  float4 v = ((const float4*)Y2)[t];
  float4 A = ((const float4*)a2)[d4];
  float4 C = ((const float4*)c2)[d4];
  float4 o;
  o.x = fmaxf(v.x*A.x + C.x, 0.f);
  o.y = fmaxf(v.y*A.y + C.y, 0.f);
  o.z = fmaxf(v.z*A.z + C.z, 0.f);
  o.w = fmaxf(v.w*A.w + C.w, 0.f);
  ((float4*)out)[t] = o;
}

extern "C" void kernel_launch(void* const* d_in, const int* in_sizes, int n_in,
                              void* d_out, int out_size, void* d_ws, size_t ws_size,
                              hipStream_t stream){
  const float* x   = (const float*)d_in[0];
  const float* ea  = (const float*)d_in[1];
  const float* deg = (const float*)d_in[2];
  const float* eps = (const float*)d_in[3];
  const float* W1  = (const float*)d_in[4];
  const float* g1  = (const float*)d_in[5];
  const float* b1  = (const float*)d_in[6];
  const float* W2  = (const float*)d_in[7];
  const float* g2  = (const float*)d_in[8];
  const float* b2  = (const float*)d_in[9];
  const int* src   = (const int*)d_in[10];
  const int* dst   = (const int*)d_in[11];
  float* out = (float*)d_out;

  int N = in_sizes[2];
  int E = in_sizes[10];

  // tiny workspace: ~232 KB total (no big intermediates — h/Y2 live in d_out)
  char* w = (char*)d_ws;
  size_t off = 0;
  short* W1s = (short*)(w + off); off += (size_t)H*D*2;   // 64 KB swizzled bf16
  short* W2s = (short*)(w + off); off += (size_t)D*H*2;   // 64 KB
  float* st1 = (float*)(w + off); off += 32*2*H*4;        // 64 KB shadow sum/sumsq
  float* st2 = (float*)(w + off); off += 32*2*D*4;        // 32 KB
  float* a1  = (float*)(w + off); off += H*4;
  float* c1  = (float*)(w + off); off += H*4;
  float* a2  = (float*)(w + off); off += D*4;
  float* c2  = (float*)(w + off); off += D*4;

  float* h = out;                                         // [N,128] staging in d_out

  hipLaunchKernelGGL(k_prep, dim3(352), dim3(256), 0, stream, W1, W2, W1s, W2s, st1, st2);
  int total4 = N*(D/4);
  hipLaunchKernelGGL(k_init_h, dim3((total4+255)/256), dim3(256), 0, stream, x, deg, eps, h, total4);
  hipLaunchKernelGGL(k_scatter, dim3((E+3)/4), dim3(256), 0, stream, x, ea, src, dst, h, E);
  int nW = (N + 15)/16;
  int gb = (nW + 3)/4;
  hipLaunchKernelGGL(k_gemm1, dim3(gb), dim3(256), 0, stream, h, W1s, st1, nW);
  hipLaunchKernelGGL(k_fin1, dim3(1), dim3(H), 0, stream, st1, g1, b1, a1, c1, 1.0f/(float)N);
  hipLaunchKernelGGL(k_gemm2, dim3(gb), dim3(256), 0, stream, h, W1s, W2s, a1, c1, h, st2, nW);
  hipLaunchKernelGGL(k_fin2, dim3(1), dim3(D), 0, stream, st2, g2, b2, a2, c2, 1.0f/(float)N);
  hipLaunchKernelGGL(k_final, dim3((total4+255)/256), dim3(256), 0, stream, h, a2, c2, out, total4);
}

// Round 4
// 1072.877 us; speedup vs baseline: 1.3795x; 1.3795x over previous
//
#include <hip/hip_runtime.h>
#include <stdint.h>

#define D 128
#define H 256
#define LSTR 264   // LDS row stride in shorts (padded vs 256 to break bank conflicts)

typedef short s8v __attribute__((ext_vector_type(8)));   // 8 x bf16 fragment (4 VGPRs)
typedef float f4v __attribute__((ext_vector_type(4)));   // 4 x f32 accumulator

__device__ __forceinline__ short f2bf(float f){
  union { float f; unsigned u; } v; v.f = f;
  unsigned r = v.u + 0x7fffu + ((v.u >> 16) & 1u);       // round-to-nearest-even
  return (short)(r >> 16);
}

// ---- prep: swizzle W1,W2 into bf16 MFMA B-fragment order; zero stats + counts ----
__global__ void k_prep(const float* __restrict__ W1, const float* __restrict__ W2,
                       short* __restrict__ W1s, short* __restrict__ W2s,
                       float* __restrict__ st1, float* __restrict__ st2,
                       int* __restrict__ counts, int N_){
  int t = blockIdx.x*256 + threadIdx.x;
  if (t < 32768){                               // W1 [H=256][D=128], 16 jt x 4 kt
    int j = t & 7, lane = (t>>3) & 63, kt = (t>>9) & 3, jt = t>>11;
    int col = jt*16 + (lane & 15);
    int k   = kt*32 + (lane>>4)*8 + j;
    W1s[t] = f2bf(W1[col*D + k]);
  } else if (t < 65536){                        // W2 [D=128][H=256], 8 jt x 8 kt
    int u = t - 32768;
    int j = u & 7, lane = (u>>3) & 63, kt = (u>>9) & 7, jt = u>>12;
    int col = jt*16 + (lane & 15);
    int k   = kt*32 + (lane>>4)*8 + j;
    W2s[u] = f2bf(W2[col*H + k]);
  } else if (t < 90112){
    int u = t - 65536;
    if (u < 32*2*H) st1[u] = 0.f;
    else st2[u - 32*2*H] = 0.f;                 // 32*2*D entries
  } else {
    int u = t - 90112;
    if (u <= N_) counts[u] = 0;
  }
}

// ---- CSR build step 1: per-node incidence counts ----
__global__ void k_count(const int* __restrict__ src, const int* __restrict__ dst,
                        int* __restrict__ counts, int E_){
  int e = blockIdx.x*256 + threadIdx.x;
  if (e >= E_) return;
  atomicAdd(&counts[src[e]], 1);
  atomicAdd(&counts[dst[e]], 1);
}

// ---- CSR build step 2: single-block exclusive scan (N=100k) ----
__global__ void k_scan(const int* __restrict__ counts, int* __restrict__ offsets,
                       int* __restrict__ cursor, int N_){
  __shared__ int part[1024];
  int t = threadIdx.x;
  int chunk = (N_ + 1023) >> 10;
  int lo = t*chunk, hi = min(lo + chunk, N_);
  int s = 0;
  for (int i=lo; i<hi; i++) s += counts[i];
  part[t] = s;
  __syncthreads();
  for (int o=1; o<1024; o<<=1){                 // Hillis-Steele inclusive scan
    int v = (t >= o) ? part[t-o] : 0;
    __syncthreads();
    part[t] += v;
    __syncthreads();
  }
  int base = part[t] - s;                       // exclusive prefix
  for (int i=lo; i<hi; i++){
    offsets[i] = base; cursor[i] = base;
    base += counts[i];
  }
  if (t == 0) offsets[N_] = part[1023];
}

// ---- CSR build step 3: fill entry lists. entry = (e<<1)|side, side=1 => at src ----
__global__ void k_fill(const int* __restrict__ src, const int* __restrict__ dst,
                       int* __restrict__ cursor, int* __restrict__ entries, int E_){
  int e = blockIdx.x*256 + threadIdx.x;
  if (e >= E_) return;
  int p = atomicAdd(&cursor[src[e]], 1);
  entries[p] = (e<<1) | 1;
  int q = atomicAdd(&cursor[dst[e]], 1);
  entries[q] = (e<<1);
}

// ---- gather: h[n] = (1+eps)*x[n] + sum_inc( x[other] + ea[e] ). One wave/node. ----
__global__ void k_gather(const float* __restrict__ x, const float* __restrict__ ea,
                         const int* __restrict__ src, const int* __restrict__ dst,
                         const int* __restrict__ offsets, const int* __restrict__ entries,
                         const float* __restrict__ eps, float* __restrict__ h, int N_){
  int n = (blockIdx.x*256 + threadIdx.x) >> 6;
  int lane = threadIdx.x & 63;
  if (n >= N_) return;
  int lo = offsets[n], hi = offsets[n+1];
  float2 xr = ((const float2*)(x + (size_t)n*D))[lane];
  float sc = 1.0f + eps[0];
  float ax = sc*xr.x, ay = sc*xr.y;
  for (int base = lo; base < hi; base += 64){
    int cnt = min(64, hi - base);
    int ent = 0, oth = 0;
    if (lane < cnt){
      ent = entries[base + lane];
      int e = ent >> 1;
      oth = (ent & 1) ? dst[e] : src[e];
    }
    int j = 0;
    for (; j+1 < cnt; j += 2){                  // 2-way unroll: 4 row loads in flight
      int e0 = __shfl(ent, j)   >> 1, o0 = __shfl(oth, j);
      int e1 = __shfl(ent, j+1) >> 1, o1 = __shfl(oth, j+1);
      float2 m0 = ((const float2*)(ea + (size_t)e0*D))[lane];
      float2 x0 = ((const float2*)(x  + (size_t)o0*D))[lane];
      float2 m1 = ((const float2*)(ea + (size_t)e1*D))[lane];
      float2 x1 = ((const float2*)(x  + (size_t)o1*D))[lane];
      ax += m0.x + x0.x + m1.x + x1.x;
      ay += m0.y + x0.y + m1.y + x1.y;
    }
    if (j < cnt){
      int e0 = __shfl(ent, j) >> 1, o0 = __shfl(oth, j);
      float2 m0 = ((const float2*)(ea + (size_t)e0*D))[lane];
      float2 x0 = ((const float2*)(x  + (size_t)o0*D))[lane];
      ax += m0.x + x0.x;
      ay += m0.y + x0.y;
    }
  }
  float2 o; o.x = ax; o.y = ay;
  ((float2*)(h + (size_t)n*D))[lane] = o;
}

// ---- GEMM1 stats-only: col sums / sumsq of Y1 = h @ W1^T (Y1 never stored) ----
__global__ void k_gemm1(const float* __restrict__ h, const short* __restrict__ W1s,
                        float* __restrict__ st1, int nW){
  int wid = (blockIdx.x*256 + threadIdx.x) >> 6;
  int lane = threadIdx.x & 63;
  if (wid >= nW) return;
  int r0 = wid*16;
  int mrow = lane & 15, kg = lane >> 4;
  const float* hrow = h + (size_t)(r0 + mrow)*D + kg*8;
  s8v af[4];
#pragma unroll
  for (int kt=0; kt<4; kt++){
    float4 v0 = *(const float4*)(hrow + kt*32);
    float4 v1 = *(const float4*)(hrow + kt*32 + 4);
    s8v a;
    a[0]=f2bf(v0.x); a[1]=f2bf(v0.y); a[2]=f2bf(v0.z); a[3]=f2bf(v0.w);
    a[4]=f2bf(v1.x); a[5]=f2bf(v1.y); a[6]=f2bf(v1.z); a[7]=f2bf(v1.w);
    af[kt] = a;
  }
  const s8v* Bf = (const s8v*)W1s;
  int shadow = wid & 31;
#pragma unroll
  for (int jt=0; jt<16; jt++){
    f4v acc = {0.f,0.f,0.f,0.f};
#pragma unroll
    for (int kt=0; kt<4; kt++)
      acc = __builtin_amdgcn_mfma_f32_16x16x32_bf16(af[kt], Bf[(jt*4+kt)*64 + lane], acc, 0, 0, 0);
    float s = 0.f, q = 0.f;
#pragma unroll
    for (int r=0; r<4; r++){ s += acc[r]; q += acc[r]*acc[r]; }
    s += __shfl_xor(s, 16); s += __shfl_xor(s, 32);
    q += __shfl_xor(q, 16); q += __shfl_xor(q, 32);
    if (lane < 16){
      atomicAdd(&st1[shadow*(2*H) + jt*16 + lane], s);
      atomicAdd(&st1[shadow*(2*H) + H + jt*16 + lane], q);
    }
  }
}

__global__ void k_fin1(const float* __restrict__ st1, const float* __restrict__ g,
                       const float* __restrict__ b, float* __restrict__ a,
                       float* __restrict__ c, float invN){
  int j = threadIdx.x;                          // H threads
  float s=0.f, q=0.f;
  for (int i=0;i<32;i++){ s += st1[i*(2*H) + j]; q += st1[i*(2*H) + H + j]; }
  float mu = s*invN;
  float var = q*invN - mu*mu;
  float rs = rsqrtf(var + 1e-5f);
  float aa = g[j]*rs;
  a[j] = aa; c[j] = b[j] - mu*aa;
}

// ---- GEMM2 fused: recompute Y1 tile, BN1+ReLU, LDS transpose (C->A layout),
//      second MFMA chain, Y2 overwrites own h rows in d_out, BN2 stats. ----
__launch_bounds__(256)
__global__ void k_gemm2(const float* __restrict__ h, const short* __restrict__ W1s,
                        const short* __restrict__ W2s,
                        const float* __restrict__ a1, const float* __restrict__ c1,
                        float* __restrict__ Y2, float* __restrict__ st2, int nW){
  __shared__ short P[4*16*LSTR];                // 33792 B: per-wave 16x256 bf16 tile (padded)
  int wib  = threadIdx.x >> 6;
  int lane = threadIdx.x & 63;
  int wid  = blockIdx.x*4 + wib;
  bool valid = wid < nW;
  int r0 = wid*16;
  int mrow = lane & 15, kg = lane >> 4;
  short* Pw = P + wib*16*LSTR;

  // 1. h rows -> bf16 A-frags (identical to k_gemm1 => BN1 stats consistent)
  s8v af[4];
#pragma unroll
  for (int kt=0; kt<4; kt++){ s8v z = {0,0,0,0,0,0,0,0}; af[kt] = z; }
  if (valid){
    const float* hrow = h + (size_t)(r0 + mrow)*D + kg*8;
#pragma unroll
    for (int kt=0; kt<4; kt++){
      float4 v0 = *(const float4*)(hrow + kt*32);
      float4 v1 = *(const float4*)(hrow + kt*32 + 4);
      s8v a;
      a[0]=f2bf(v0.x); a[1]=f2bf(v0.y); a[2]=f2bf(v0.z); a[3]=f2bf(v0.w);
      a[4]=f2bf(v1.x); a[5]=f2bf(v1.y); a[6]=f2bf(v1.z); a[7]=f2bf(v1.w);
      af[kt] = a;
    }
  }

  // 2. recompute Y1 tile per jt, BN1+ReLU, write bf16 into LDS (C-layout positions)
  const s8v* B1 = (const s8v*)W1s;
#pragma unroll
  for (int jt=0; jt<16; jt++){
    f4v acc = {0.f,0.f,0.f,0.f};
#pragma unroll
    for (int kt=0; kt<4; kt++)
      acc = __builtin_amdgcn_mfma_f32_16x16x32_bf16(af[kt], B1[(jt*4+kt)*64 + lane], acc, 0, 0, 0);
    int col = jt*16 + mrow;
    float a = a1[col], c = c1[col];
#pragma unroll
    for (int r=0; r<4; r++){
      float e = fmaxf(acc[r]*a + c, 0.f);
      Pw[(kg*4 + r)*LSTR + col] = f2bf(e);
    }
  }
  __syncthreads();

  // 3. read back in A-frag layout: lane holds row m=lane&15, k = kt2*32 + kg*8 + j
  s8v af2[8];
#pragma unroll
  for (int kt2=0; kt2<8; kt2++)
    af2[kt2] = *(const s8v*)(Pw + mrow*LSTR + kt2*32 + kg*8);

  // 4. second GEMM + BN2 stats; Y2 overwrites this wave's own (dead) h rows
  const s8v* B2 = (const s8v*)W2s;
  int shadow = wid & 31;
#pragma unroll
  for (int jt=0; jt<8; jt++){
    f4v acc = {0.f,0.f,0.f,0.f};
#pragma unroll
    for (int kt2=0; kt2<8; kt2++)
      acc = __builtin_amdgcn_mfma_f32_16x16x32_bf16(af2[kt2], B2[(jt*8+kt2)*64 + lane], acc, 0, 0, 0);
    float s=0.f, q=0.f;
    if (valid){
#pragma unroll
      for (int r=0; r<4; r++){
        int row = r0 + kg*4 + r;
        Y2[(size_t)row*D + jt*16 + mrow] = acc[r];
        s += acc[r]; q += acc[r]*acc[r];
      }
    }
    s += __shfl_xor(s,16); s += __shfl_xor(s,32);
    q += __shfl_xor(q,16); q += __shfl_xor(q,32);
    if (valid && lane < 16){
      atomicAdd(&st2[shadow*(2*D) + jt*16 + lane], s);
      atomicAdd(&st2[shadow*(2*D) + D + jt*16 + lane], q);
    }
  }
}

__global__ void k_fin2(const float* __restrict__ st2, const float* __restrict__ g,
                       const float* __restrict__ b, float* __restrict__ a,
                       float* __restrict__ c, float invN){
  int j = threadIdx.x;                          // D threads
  float s=0.f, q=0.f;
  for (int i=0;i<32;i++){ s += st2[i*(2*D) + j]; q += st2[i*(2*D) + D + j]; }
  float mu = s*invN;
  float var = q*invN - mu*mu;
  float rs = rsqrtf(var + 1e-5f);
  float aa = g[j]*rs;
  a[j] = aa; c[j] = b[j] - mu*aa;
}

// ---- out = relu(Y2*a2 + c2), in place on d_out ----
__global__ void k_final(const float* __restrict__ Y2, const float* __restrict__ a2,
                        const float* __restrict__ c2, float* __restrict__ out, int total4){
  int t = blockIdx.x*256 + threadIdx.x;
  if (t >= total4) return;
  int d4 = t & 31;
  float4 v = ((const float4*)Y2)[t];
  float4 A = ((const float4*)a2)[d4];
  float4 C = ((const float4*)c2)[d4];
  float4 o;
  o.x = fmaxf(v.x*A.x + C.x, 0.f);
  o.y = fmaxf(v.y*A.y + C.y, 0.f);
  o.z = fmaxf(v.z*A.z + C.z, 0.f);
  o.w = fmaxf(v.w*A.w + C.w, 0.f);
  ((float4*)out)[t] = o;
}

extern "C" void kernel_launch(void* const* d_in, const int* in_sizes, int n_in,
                              void* d_out, int out_size, void* d_ws, size_t ws_size,
                              hipStream_t stream){
  const float* x   = (const float*)d_in[0];
  const float* ea  = (const float*)d_in[1];
  const float* eps = (const float*)d_in[3];
  const float* W1  = (const float*)d_in[4];
  const float* g1  = (const float*)d_in[5];
  const float* b1  = (const float*)d_in[6];
  const float* W2  = (const float*)d_in[7];
  const float* g2  = (const float*)d_in[8];
  const float* b2  = (const float*)d_in[9];
  const int* src   = (const int*)d_in[10];
  const int* dst   = (const int*)d_in[11];
  float* out = (float*)d_out;

  int N = in_sizes[2];
  int E = in_sizes[10];

  // workspace: ~6.0 MB (weights, stats, CSR)
  char* w = (char*)d_ws;
  size_t off = 0;
  short* W1s = (short*)(w + off); off += (size_t)H*D*2;   // 64 KB swizzled bf16
  short* W2s = (short*)(w + off); off += (size_t)D*H*2;   // 64 KB
  float* st1 = (float*)(w + off); off += 32*2*H*4;        // 64 KB shadow sum/sumsq
  float* st2 = (float*)(w + off); off += 32*2*D*4;        // 32 KB
  float* a1  = (float*)(w + off); off += H*4;
  float* c1  = (float*)(w + off); off += H*4;
  float* a2  = (float*)(w + off); off += D*4;
  float* c2  = (float*)(w + off); off += D*4;
  int* counts  = (int*)(w + off); off += (size_t)(N+1)*4; // 400 KB
  int* offsets = (int*)(w + off); off += (size_t)(N+1)*4; // 400 KB
  int* cursor  = (int*)(w + off); off += (size_t)N*4;     // 400 KB
  int* entries = (int*)(w + off); off += (size_t)2*E*4;   // 4.8 MB

  float* h = out;                                         // [N,128] staging in d_out

  int prepT = 90112 + N + 1;
  hipLaunchKernelGGL(k_prep, dim3((prepT+255)/256), dim3(256), 0, stream,
                     W1, W2, W1s, W2s, st1, st2, counts, N);
  int eb = (E + 255)/256;
  hipLaunchKernelGGL(k_count, dim3(eb), dim3(256), 0, stream, src, dst, counts, E);
  hipLaunchKernelGGL(k_scan, dim3(1), dim3(1024), 0, stream, counts, offsets, cursor, N);
  hipLaunchKernelGGL(k_fill, dim3(eb), dim3(256), 0, stream, src, dst, cursor, entries, E);
  hipLaunchKernelGGL(k_gather, dim3((N+3)/4), dim3(256), 0, stream,
                     x, ea, src, dst, offsets, entries, eps, h, N);
  int nW = (N + 15)/16;
  int gb = (nW + 3)/4;
  hipLaunchKernelGGL(k_gemm1, dim3(gb), dim3(256), 0, stream, h, W1s, st1, nW);
  hipLaunchKernelGGL(k_fin1, dim3(1), dim3(H), 0, stream, st1, g1, b1, a1, c1, 1.0f/(float)N);
  hipLaunchKernelGGL(k_gemm2, dim3(gb), dim3(256), 0, stream, h, W1s, W2s, a1, c1, h, st2, nW);
  hipLaunchKernelGGL(k_fin2, dim3(1), dim3(D), 0, stream, st2, g2, b2, a2, c2, 1.0f/(float)N);
  int total4 = N*(D/4);
  hipLaunchKernelGGL(k_final, dim3((total4+255)/256), dim3(256), 0, stream, h, a2, c2, out, total4);
}

// Round 5
// 851.728 us; speedup vs baseline: 1.7377x; 1.2596x over previous
//
#include <hip/hip_runtime.h>
#include <stdint.h>

#define D 128
#define H 256
#define LSTR 264   // LDS row stride in shorts (padded vs 256 to break bank conflicts)

typedef short s8v __attribute__((ext_vector_type(8)));   // 8 x bf16 fragment (4 VGPRs)
typedef float f4v __attribute__((ext_vector_type(4)));   // 4 x f32 accumulator

__device__ __forceinline__ short f2bf(float f){
  union { float f; unsigned u; } v; v.f = f;
  unsigned r = v.u + 0x7fffu + ((v.u >> 16) & 1u);       // round-to-nearest-even
  return (short)(r >> 16);
}

// ---- prep: swizzle W1,W2 into bf16 MFMA B-fragment order; zero stats + counts ----
__global__ void k_prep(const float* __restrict__ W1, const float* __restrict__ W2,
                       short* __restrict__ W1s, short* __restrict__ W2s,
                       float* __restrict__ st1, float* __restrict__ st2,
                       int* __restrict__ counts, int N_){
  int t = blockIdx.x*256 + threadIdx.x;
  if (t < 32768){                               // W1 [H=256][D=128], 16 jt x 4 kt
    int j = t & 7, lane = (t>>3) & 63, kt = (t>>9) & 3, jt = t>>11;
    int col = jt*16 + (lane & 15);
    int k   = kt*32 + (lane>>4)*8 + j;
    W1s[t] = f2bf(W1[col*D + k]);
  } else if (t < 65536){                        // W2 [D=128][H=256], 8 jt x 8 kt
    int u = t - 32768;
    int j = u & 7, lane = (u>>3) & 63, kt = (u>>9) & 7, jt = u>>12;
    int col = jt*16 + (lane & 15);
    int k   = kt*32 + (lane>>4)*8 + j;
    W2s[u] = f2bf(W2[col*H + k]);
  } else if (t < 90112){
    int u = t - 65536;
    if (u < 32*2*H) st1[u] = 0.f;
    else st2[u - 32*2*H] = 0.f;                 // 32*2*D entries
  } else {
    int u = t - 90112;
    if (u <= N_) counts[u] = 0;
  }
}

// ---- CSR build step 1: per-node incidence counts ----
__global__ void k_count(const int* __restrict__ src, const int* __restrict__ dst,
                        int* __restrict__ counts, int E_){
  int e = blockIdx.x*256 + threadIdx.x;
  if (e >= E_) return;
  atomicAdd(&counts[src[e]], 1);
  atomicAdd(&counts[dst[e]], 1);
}

// ---- CSR build step 2a: per-block sums (1024 counts/block) ----
__global__ void k_scanA(const int* __restrict__ counts, int* __restrict__ blockSums, int N_){
  int t = threadIdx.x;
  int base = blockIdx.x*1024 + t*4;
  int s = 0;
  if (base + 3 < N_){
    int4 v = *(const int4*)(counts + base);
    s = v.x + v.y + v.z + v.w;
  } else {
    for (int i=0;i<4;i++) if (base+i < N_) s += counts[base+i];
  }
  __shared__ int ws4[4];
  for (int o=1; o<64; o<<=1) s += __shfl_xor(s, o);
  if ((t & 63) == 0) ws4[t>>6] = s;
  __syncthreads();
  if (t == 0) blockSums[blockIdx.x] = ws4[0]+ws4[1]+ws4[2]+ws4[3];
}

// ---- CSR build step 2b: scan block sums (single small block), total -> offsets[N] ----
__global__ void k_scanB(const int* __restrict__ blockSums, int* __restrict__ blockBase,
                        int* __restrict__ offsets, int nb, int N_){
  __shared__ int part[1024];
  int t = threadIdx.x;
  int v = (t < nb) ? blockSums[t] : 0;
  part[t] = v;
  __syncthreads();
  for (int o=1; o<1024; o<<=1){
    int u = (t >= o) ? part[t-o] : 0;
    __syncthreads();
    part[t] += u;
    __syncthreads();
  }
  if (t < nb) blockBase[t] = part[t] - v;       // exclusive
  if (t == nb-1) offsets[N_] = part[t];
}

// ---- CSR build step 2c: per-block exclusive scan + global base -> offsets/cursor ----
__global__ void k_scanC(const int* __restrict__ counts, const int* __restrict__ blockBase,
                        int* __restrict__ offsets, int* __restrict__ cursor, int N_){
  __shared__ int part[256];
  int t = threadIdx.x;
  int base = blockIdx.x*1024 + t*4;
  int c[4]; int s = 0;
#pragma unroll
  for (int i=0;i<4;i++){ c[i] = (base+i < N_) ? counts[base+i] : 0; s += c[i]; }
  part[t] = s;
  __syncthreads();
  for (int o=1; o<256; o<<=1){
    int u = (t >= o) ? part[t-o] : 0;
    __syncthreads();
    part[t] += u;
    __syncthreads();
  }
  int pos = blockBase[blockIdx.x] + part[t] - s;
#pragma unroll
  for (int i=0;i<4;i++){
    if (base+i < N_){ offsets[base+i] = pos; cursor[base+i] = pos; pos += c[i]; }
  }
}

// ---- CSR build step 3: fill entry lists. entry = (e<<1)|side, side=1 => at src ----
__global__ void k_fill(const int* __restrict__ src, const int* __restrict__ dst,
                       int* __restrict__ cursor, int* __restrict__ entries, int E_){
  int e = blockIdx.x*256 + threadIdx.x;
  if (e >= E_) return;
  int p = atomicAdd(&cursor[src[e]], 1);
  entries[p] = (e<<1) | 1;
  int q = atomicAdd(&cursor[dst[e]], 1);
  entries[q] = (e<<1);
}

// ---- gather: h[n] = (1+eps)*x[n] + sum_inc( x[other] + ea[e] ). One wave/node. ----
__global__ void k_gather(const float* __restrict__ x, const float* __restrict__ ea,
                         const int* __restrict__ src, const int* __restrict__ dst,
                         const int* __restrict__ offsets, const int* __restrict__ entries,
                         const float* __restrict__ eps, float* __restrict__ h, int N_){
  int n = (blockIdx.x*256 + threadIdx.x) >> 6;
  int lane = threadIdx.x & 63;
  if (n >= N_) return;
  int lo = offsets[n], hi = offsets[n+1];
  float2 xr = ((const float2*)(x + (size_t)n*D))[lane];
  float sc = 1.0f + eps[0];
  float ax = sc*xr.x, ay = sc*xr.y;
  for (int base = lo; base < hi; base += 64){
    int cnt = min(64, hi - base);
    int ent = 0, oth = 0;
    if (lane < cnt){
      ent = entries[base + lane];
      int e = ent >> 1;
      oth = (ent & 1) ? dst[e] : src[e];
    }
    int j = 0;
    for (; j+3 < cnt; j += 4){                  // 4-way unroll: 8 row loads in flight
      int e0 = __shfl(ent, j)   >> 1, o0 = __shfl(oth, j);
      int e1 = __shfl(ent, j+1) >> 1, o1 = __shfl(oth, j+1);
      int e2 = __shfl(ent, j+2) >> 1, o2 = __shfl(oth, j+2);
      int e3 = __shfl(ent, j+3) >> 1, o3 = __shfl(oth, j+3);
      float2 m0 = ((const float2*)(ea + (size_t)e0*D))[lane];
      float2 x0 = ((const float2*)(x  + (size_t)o0*D))[lane];
      float2 m1 = ((const float2*)(ea + (size_t)e1*D))[lane];
      float2 x1 = ((const float2*)(x  + (size_t)o1*D))[lane];
      float2 m2 = ((const float2*)(ea + (size_t)e2*D))[lane];
      float2 x2 = ((const float2*)(x  + (size_t)o2*D))[lane];
      float2 m3 = ((const float2*)(ea + (size_t)e3*D))[lane];
      float2 x3 = ((const float2*)(x  + (size_t)o3*D))[lane];
      ax += (m0.x + x0.x) + (m1.x + x1.x) + (m2.x + x2.x) + (m3.x + x3.x);
      ay += (m0.y + x0.y) + (m1.y + x1.y) + (m2.y + x2.y) + (m3.y + x3.y);
    }
    for (; j < cnt; j++){
      int e0 = __shfl(ent, j) >> 1, o0 = __shfl(oth, j);
      float2 m0 = ((const float2*)(ea + (size_t)e0*D))[lane];
      float2 x0 = ((const float2*)(x  + (size_t)o0*D))[lane];
      ax += m0.x + x0.x;
      ay += m0.y + x0.y;
    }
  }
  float2 o; o.x = ax; o.y = ay;
  ((float2*)(h + (size_t)n*D))[lane] = o;
}

// ---- GEMM1 stats-only: col sums / sumsq of Y1 = h @ W1^T (Y1 never stored) ----
__global__ void k_gemm1(const float* __restrict__ h, const short* __restrict__ W1s,
                        float* __restrict__ st1, int nW){
  int wid = (blockIdx.x*256 + threadIdx.x) >> 6;
  int lane = threadIdx.x & 63;
  if (wid >= nW) return;
  int r0 = wid*16;
  int mrow = lane & 15, kg = lane >> 4;
  const float* hrow = h + (size_t)(r0 + mrow)*D + kg*8;
  s8v af[4];
#pragma unroll
  for (int kt=0; kt<4; kt++){
    float4 v0 = *(const float4*)(hrow + kt*32);
    float4 v1 = *(const float4*)(hrow + kt*32 + 4);
    s8v a;
    a[0]=f2bf(v0.x); a[1]=f2bf(v0.y); a[2]=f2bf(v0.z); a[3]=f2bf(v0.w);
    a[4]=f2bf(v1.x); a[5]=f2bf(v1.y); a[6]=f2bf(v1.z); a[7]=f2bf(v1.w);
    af[kt] = a;
  }
  const s8v* Bf = (const s8v*)W1s;
  int shadow = wid & 31;
#pragma unroll
  for (int jt=0; jt<16; jt++){
    f4v acc = {0.f,0.f,0.f,0.f};
#pragma unroll
    for (int kt=0; kt<4; kt++)
      acc = __builtin_amdgcn_mfma_f32_16x16x32_bf16(af[kt], Bf[(jt*4+kt)*64 + lane], acc, 0, 0, 0);
    float s = 0.f, q = 0.f;
#pragma unroll
    for (int r=0; r<4; r++){ s += acc[r]; q += acc[r]*acc[r]; }
    s += __shfl_xor(s, 16); s += __shfl_xor(s, 32);
    q += __shfl_xor(q, 16); q += __shfl_xor(q, 32);
    if (lane < 16){
      atomicAdd(&st1[shadow*(2*H) + jt*16 + lane], s);
      atomicAdd(&st1[shadow*(2*H) + H + jt*16 + lane], q);
    }
  }
}

__global__ void k_fin1(const float* __restrict__ st1, const float* __restrict__ g,
                       const float* __restrict__ b, float* __restrict__ a,
                       float* __restrict__ c, float invN){
  int j = threadIdx.x;                          // H threads
  float s=0.f, q=0.f;
  for (int i=0;i<32;i++){ s += st1[i*(2*H) + j]; q += st1[i*(2*H) + H + j]; }
  float mu = s*invN;
  float var = q*invN - mu*mu;
  float rs = rsqrtf(var + 1e-5f);
  float aa = g[j]*rs;
  a[j] = aa; c[j] = b[j] - mu*aa;
}

// ---- GEMM2 fused: recompute Y1 tile, BN1+ReLU, LDS transpose (C->A layout),
//      second MFMA chain, Y2 overwrites own h rows in d_out, BN2 stats. ----
__launch_bounds__(256)
__global__ void k_gemm2(const float* __restrict__ h, const short* __restrict__ W1s,
                        const short* __restrict__ W2s,
                        const float* __restrict__ a1, const float* __restrict__ c1,
                        float* __restrict__ Y2, float* __restrict__ st2, int nW){
  __shared__ short P[4*16*LSTR];                // 33792 B: per-wave 16x256 bf16 tile (padded)
  int wib  = threadIdx.x >> 6;
  int lane = threadIdx.x & 63;
  int wid  = blockIdx.x*4 + wib;
  bool valid = wid < nW;
  int r0 = wid*16;
  int mrow = lane & 15, kg = lane >> 4;
  short* Pw = P + wib*16*LSTR;

  // 1. h rows -> bf16 A-frags (identical to k_gemm1 => BN1 stats consistent)
  s8v af[4];
#pragma unroll
  for (int kt=0; kt<4; kt++){ s8v z = {0,0,0,0,0,0,0,0}; af[kt] = z; }
  if (valid){
    const float* hrow = h + (size_t)(r0 + mrow)*D + kg*8;
#pragma unroll
    for (int kt=0; kt<4; kt++){
      float4 v0 = *(const float4*)(hrow + kt*32);
      float4 v1 = *(const float4*)(hrow + kt*32 + 4);
      s8v a;
      a[0]=f2bf(v0.x); a[1]=f2bf(v0.y); a[2]=f2bf(v0.z); a[3]=f2bf(v0.w);
      a[4]=f2bf(v1.x); a[5]=f2bf(v1.y); a[6]=f2bf(v1.z); a[7]=f2bf(v1.w);
      af[kt] = a;
    }
  }

  // 2. recompute Y1 tile per jt, BN1+ReLU, write bf16 into LDS (C-layout positions)
  const s8v* B1 = (const s8v*)W1s;
#pragma unroll
  for (int jt=0; jt<16; jt++){
    f4v acc = {0.f,0.f,0.f,0.f};
#pragma unroll
    for (int kt=0; kt<4; kt++)
      acc = __builtin_amdgcn_mfma_f32_16x16x32_bf16(af[kt], B1[(jt*4+kt)*64 + lane], acc, 0, 0, 0);
    int col = jt*16 + mrow;
    float a = a1[col], c = c1[col];
#pragma unroll
    for (int r=0; r<4; r++){
      float e = fmaxf(acc[r]*a + c, 0.f);
      Pw[(kg*4 + r)*LSTR + col] = f2bf(e);
    }
  }
  __syncthreads();

  // 3. read back in A-frag layout: lane holds row m=lane&15, k = kt2*32 + kg*8 + j
  s8v af2[8];
#pragma unroll
  for (int kt2=0; kt2<8; kt2++)
    af2[kt2] = *(const s8v*)(Pw + mrow*LSTR + kt2*32 + kg*8);

  // 4. second GEMM + BN2 stats; Y2 overwrites this wave's own (dead) h rows
  const s8v* B2 = (const s8v*)W2s;
  int shadow = wid & 31;
#pragma unroll
  for (int jt=0; jt<8; jt++){
    f4v acc = {0.f,0.f,0.f,0.f};
#pragma unroll
    for (int kt2=0; kt2<8; kt2++)
      acc = __builtin_amdgcn_mfma_f32_16x16x32_bf16(af2[kt2], B2[(jt*8+kt2)*64 + lane], acc, 0, 0, 0);
    float s=0.f, q=0.f;
    if (valid){
#pragma unroll
      for (int r=0; r<4; r++){
        int row = r0 + kg*4 + r;
        Y2[(size_t)row*D + jt*16 + mrow] = acc[r];
        s += acc[r]; q += acc[r]*acc[r];
      }
    }
    s += __shfl_xor(s,16); s += __shfl_xor(s,32);
    q += __shfl_xor(q,16); q += __shfl_xor(q,32);
    if (valid && lane < 16){
      atomicAdd(&st2[shadow*(2*D) + jt*16 + lane], s);
      atomicAdd(&st2[shadow*(2*D) + D + jt*16 + lane], q);
    }
  }
}

__global__ void k_fin2(const float* __restrict__ st2, const float* __restrict__ g,
                       const float* __restrict__ b, float* __restrict__ a,
                       float* __restrict__ c, float invN){
  int j = threadIdx.x;                          // D threads
  float s=0.f, q=0.f;
  for (int i=0;i<32;i++){ s += st2[i*(2*D) + j]; q += st2[i*(2*D) + D + j]; }
  float mu = s*invN;
  float var = q*invN - mu*mu;
  float rs = rsqrtf(var + 1e-5f);
  float aa = g[j]*rs;
  a[j] = aa; c[j] = b[j] - mu*aa;
}

// ---- out = relu(Y2*a2 + c2), in place on d_out ----
__global__ void k_final(const float* __restrict__ Y2, const float* __restrict__ a2,
                        const float* __restrict__ c2, float* __restrict__ out, int total4){
  int t = blockIdx.x*256 + threadIdx.x;
  if (t >= total4) return;
  int d4 = t & 31;
  float4 v = ((const float4*)Y2)[t];
  float4 A = ((const float4*)a2)[d4];
  float4 C = ((const float4*)c2)[d4];
  float4 o;
  o.x = fmaxf(v.x*A.x + C.x, 0.f);
  o.y = fmaxf(v.y*A.y + C.y, 0.f);
  o.z = fmaxf(v.z*A.z + C.z, 0.f);
  o.w = fmaxf(v.w*A.w + C.w, 0.f);
  ((float4*)out)[t] = o;
}

extern "C" void kernel_launch(void* const* d_in, const int* in_sizes, int n_in,
                              void* d_out, int out_size, void* d_ws, size_t ws_size,
                              hipStream_t stream){
  const float* x   = (const float*)d_in[0];
  const float* ea  = (const float*)d_in[1];
  const float* eps = (const float*)d_in[3];
  const float* W1  = (const float*)d_in[4];
  const float* g1  = (const float*)d_in[5];
  const float* b1  = (const float*)d_in[6];
  const float* W2  = (const float*)d_in[7];
  const float* g2  = (const float*)d_in[8];
  const float* b2  = (const float*)d_in[9];
  const int* src   = (const int*)d_in[10];
  const int* dst   = (const int*)d_in[11];
  float* out = (float*)d_out;

  int N = in_sizes[2];
  int E = in_sizes[10];

  // workspace: ~5.6 MB (weights, stats, CSR)
  char* w = (char*)d_ws;
  size_t off = 0;
  short* W1s = (short*)(w + off); off += (size_t)H*D*2;   // 64 KB swizzled bf16
  short* W2s = (short*)(w + off); off += (size_t)D*H*2;   // 64 KB
  float* st1 = (float*)(w + off); off += 32*2*H*4;        // 64 KB shadow sum/sumsq
  float* st2 = (float*)(w + off); off += 32*2*D*4;        // 32 KB
  float* a1  = (float*)(w + off); off += H*4;
  float* c1  = (float*)(w + off); off += H*4;
  float* a2  = (float*)(w + off); off += D*4;
  float* c2  = (float*)(w + off); off += D*4;
  int* counts  = (int*)(w + off); off += (size_t)(N+1)*4; // 400 KB
  int* offsets = (int*)(w + off); off += (size_t)(N+1)*4; // 400 KB
  int* cursor  = (int*)(w + off); off += (size_t)N*4;     // 400 KB
  int* blockSums = (int*)(w + off); off += 1024*4;        // 4 KB
  int* blockBase = (int*)(w + off); off += 1024*4;        // 4 KB
  int* entries = (int*)(w + off); off += (size_t)2*E*4;   // 4.8 MB

  float* h = out;                                         // [N,128] staging in d_out

  int prepT = 90112 + N + 1;
  hipLaunchKernelGGL(k_prep, dim3((prepT+255)/256), dim3(256), 0, stream,
                     W1, W2, W1s, W2s, st1, st2, counts, N);
  int eb = (E + 255)/256;
  hipLaunchKernelGGL(k_count, dim3(eb), dim3(256), 0, stream, src, dst, counts, E);
  int nb = (N + 1023)/1024;                               // 98 blocks
  hipLaunchKernelGGL(k_scanA, dim3(nb), dim3(256), 0, stream, counts, blockSums, N);
  hipLaunchKernelGGL(k_scanB, dim3(1), dim3(1024), 0, stream, blockSums, blockBase, offsets, nb, N);
  hipLaunchKernelGGL(k_scanC, dim3(nb), dim3(256), 0, stream, counts, blockBase, offsets, cursor, N);
  hipLaunchKernelGGL(k_fill, dim3(eb), dim3(256), 0, stream, src, dst, cursor, entries, E);
  hipLaunchKernelGGL(k_gather, dim3((N+3)/4), dim3(256), 0, stream,
                     x, ea, src, dst, offsets, entries, eps, h, N);
  int nW = (N + 15)/16;
  int gb = (nW + 3)/4;
  hipLaunchKernelGGL(k_gemm1, dim3(gb), dim3(256), 0, stream, h, W1s, st1, nW);
  hipLaunchKernelGGL(k_fin1, dim3(1), dim3(H), 0, stream, st1, g1, b1, a1, c1, 1.0f/(float)N);
  hipLaunchKernelGGL(k_gemm2, dim3(gb), dim3(256), 0, stream, h, W1s, W2s, a1, c1, h, st2, nW);
  hipLaunchKernelGGL(k_fin2, dim3(1), dim3(D), 0, stream, st2, g2, b2, a2, c2, 1.0f/(float)N);
  int total4 = N*(D/4);
  hipLaunchKernelGGL(k_final, dim3((total4+255)/256), dim3(256), 0, stream, h, a2, c2, out, total4);
}